// Round 15
// baseline (737.117 us; speedup 1.0000x reference)
//
#include <hip/hip_runtime.h>
#include <math.h>

#define BB 512
#define NN 16
#define CC 256
#define KK 8192
#define BNC (BB*NN*CC)

typedef unsigned short u16;
typedef __attribute__((ext_vector_type(8))) short bf16x8;
typedef __attribute__((ext_vector_type(4))) float f32x4;

__device__ __forceinline__ u16 f2bf(float x) {
    unsigned u = __float_as_uint(x);
    unsigned r = (u + 0x7fffu + ((u >> 16) & 1u)) >> 16;
    return (u16)r;
}

__device__ __forceinline__ void gl2lds16(const void* g, void* l) {
    __builtin_amdgcn_global_load_lds(
        (const __attribute__((address_space(1))) void*)g,
        (__attribute__((address_space(3))) void*)l,
        16, 0, 0);
}

__device__ __forceinline__ void gl2lds4(const void* g, void* l) {
    __builtin_amdgcn_global_load_lds(
        (const __attribute__((address_space(1))) void*)g,
        (__attribute__((address_space(3))) void*)l,
        4, 0, 0);
}

// ---------------------------------------------------------------------------
// merged: stores negated-bf16 emb AND 0.5*|e|^2 from one pass over emb.
__global__ void esq_cvt_kernel(const float* __restrict__ emb,
                               float* __restrict__ e_sq,
                               u16* __restrict__ out) {
    int gid = blockIdx.x * blockDim.x + threadIdx.x;
    int lane = gid & 63;
    float4 v = ((const float4*)emb)[gid];
    ushort4 o;
    o.x = f2bf(-v.x); o.y = f2bf(-v.y); o.z = f2bf(-v.z); o.w = f2bf(-v.w);
    ((ushort4*)out)[gid] = o;
    float s = v.x*v.x + v.y*v.y + v.z*v.z + v.w*v.w;
    #pragma unroll
    for (int m = 32; m >= 1; m >>= 1) s += __shfl_xor(s, m, 64);
    if (lane == 0) e_sq[gid >> 6] = 0.5f * s;
}

// initial pool for pn=1
__global__ void init_pool_kernel(const float* __restrict__ f,
                                 u16* __restrict__ rest_bf) {
    int b = blockIdx.x;
    int c = threadIdx.x;
    const float* base = f + (size_t)b * NN * CC + c;
    float acc = 0.f;
    #pragma unroll
    for (int n = 0; n < NN; ++n) acc += base[(size_t)n * CC];
    rest_bf[(size_t)b * CC + c] = f2bf(acc * (1.0f / 16.0f));
}

// ---------------------------------------------------------------------------
__device__ __forceinline__ unsigned long long shfl_xor_u64(unsigned long long v, int m) {
    unsigned lo = (unsigned)v, hi = (unsigned)(v >> 32);
    lo = __shfl_xor(lo, m, 64);
    hi = __shfl_xor(hi, m, 64);
    return ((unsigned long long)hi << 32) | lo;
}

// MFMA distance+argmin, v16 (templated rows-per-wave; v14 drain schedule):
//  Per-CU floors: MFMA 16.5us (fixed); LDS-read = 41us/J (J = 16-row tiles
//  per wave). v14/v15 (J=2, 16 waves/CU) were LDS-bound at 20.5; v8 (J=4)
//  had 10.2 but duplicated staging across its 2 blocks. v16 J=4: ONE
//  512-thread 8-wave block of 512 rows/CU -> j=4 LDS ratio AND v14's wave
//  count AND chunk staged once per CU (L2 code traffic halved).
//  - Register regime (the v10/v11 lesson, applied deliberately): J=4 pads
//    LDS to 84KB so LDS-implied occupancy = 1 block/CU -> allocator budget
//    2 waves/SIMD = 256 regs -> demand ~220 fits, no spill. J=2 keeps the
//    proven 66KB (2-block regime, 96 regs, v14-verified).
//  - Schedule = v14's (best measured): cb-level double buffer in first
//    64KB, burst-stage next cb, compute 8 chunks, fold, vmcnt(0)+barrier.
//  - gx granule swizzle via pre-swizzled global source: 0 bank conflicts
//    (proven v6-v15). No setprio, no sched_barrier.
template <int J>
__global__ __launch_bounds__(512, 2) void dist_mfma_kernel(
        const u16* __restrict__ A, const u16* __restrict__ Bm,
        const float* __restrict__ e_sq,
        unsigned long long* __restrict__ packed, int cpb) {
    // J=4: 41984 u16 = 82KB (+2KB sE = 84KB > 80KB -> 1 block/CU).
    // J=2: 32768 u16 = 64KB (+2KB sE = 66KB -> 2 blocks/CU, v14 regime).
    constexpr int SCSIZE = (J == 4) ? 41984 : 32768;
    __shared__ __align__(16) u16 sC[SCSIZE];  // ring = first 64KB (2 x 32KB)
    __shared__ __align__(16) float sE[512];   // whole esq strip (cpb <= 512)
    const int tid = threadIdx.x;
    const int w = tid >> 6, l = tid & 63;     // 8 waves
    const int r0 = blockIdx.x * (128 * J);
    const int c0 = blockIdx.y * cpb;
    const int ncb2 = cpb >> 6;   // 64-code cb-groups
    const int arow = l & 15;
    const int aq   = l >> 4;

    // ---- resident row fragments: wave owns rows r0 + w*16J .. +16J-1 ----
    bf16x8 bf[J][8];
    {
        const u16* fb = A + (((size_t)(r0 + w * 16 * J + arow)) << 8) + aq * 8;
        #pragma unroll
        for (int j = 0; j < J; ++j)
            #pragma unroll
            for (int kc = 0; kc < 8; ++kc)
                bf[j][kc] = *(const bf16x8*)(fb + (j << 12) + (kc << 5));
    }

    // ---- esq strip staged whole in prologue (cpb <= 512) ----
    for (int n = tid; n < cpb; n += 512)
        gl2lds4(e_sq + c0 + n, (char*)sE + (size_t)(n - l) * 4);

    // ---- code staging: wave w stages chunk w of each cb (4 x gl2lds16).
    // issue i covers codes i*16 + (l>>2); stored granule (l&3) receives
    // actual granule g = (l&3)^((l>>3)&3) (pre-swizzled source).
    const int g = (l & 3) ^ ((l >> 3) & 3);
    const u16* Pb = Bm + (((size_t)(c0 + (l >> 2))) << 8) + g * 8;

    #define STAGE_CB(cb_) { \
        const u16* s0_ = Pb + ((size_t)(cb_) << 14) + (w << 5); \
        char* d0_ = (char*)sC + (((cb_) & 1) << 15) + (w << 12); \
        _Pragma("unroll") \
        for (int i_ = 0; i_ < 4; ++i_) \
            gl2lds16(s0_ + (i_ << 12), d0_ + (i_ << 10)); }

    STAGE_CB(0)

    const int gx = aq ^ ((arow >> 1) & 3);   // read-side granule swizzle
    float bestd[J];
    int   bestk[J];
    #pragma unroll
    for (int j = 0; j < J; ++j) { bestd[j] = 1e30f; bestk[j] = 0; }

    asm volatile("s_waitcnt vmcnt(0)" ::: "memory");
    __builtin_amdgcn_s_barrier();
    asm volatile("" ::: "memory");

    for (int cb = 0; cb < ncb2; ++cb) {
        // burst-issue next cb's stages (max flight time before the drain)
        if (cb + 1 < ncb2) STAGE_CB(cb + 1)

        f32x4 acc[4][J];
        #pragma unroll
        for (int i = 0; i < 4; ++i) {
            f32x4 ev = *(const f32x4*)(sE + cb * 64 + i * 16 + (aq << 2));
            #pragma unroll
            for (int j = 0; j < J; ++j) acc[i][j] = ev;
        }

        const u16* bufp = sC + ((cb & 1) << 14);   // u16 units: 32KB buffer
        #pragma unroll
        for (int c = 0; c < 8; ++c) {
            bf16x8 cf[4];
            const u16* cbp = bufp + (c << 11);
            #pragma unroll
            for (int i = 0; i < 4; ++i)
                cf[i] = *(const bf16x8*)(cbp + ((i * 16 + arow) << 5) + (gx << 3));
            #pragma unroll
            for (int i = 0; i < 4; ++i)
                #pragma unroll
                for (int j = 0; j < J; ++j)
                    acc[i][j] = __builtin_amdgcn_mfma_f32_16x16x32_bf16(
                                    cf[i], bf[j][c], acc[i][j], 0, 0, 0);
        }

        // fold (register-only; overlaps tail of in-flight stages)
        #pragma unroll
        for (int i = 0; i < 4; ++i)
            #pragma unroll
            for (int r = 0; r < 4; ++r) {
                const int k = c0 + cb * 64 + i * 16 + (aq << 2) + r;
                #pragma unroll
                for (int j = 0; j < J; ++j) {
                    const float d = acc[i][j][r];
                    if (d < bestd[j]) { bestd[j] = d; bestk[j] = k; }
                }
            }

        // own stages for cb+1 complete; reads of this buffer retired
        asm volatile("s_waitcnt vmcnt(0) lgkmcnt(0)" ::: "memory");
        __builtin_amdgcn_s_barrier();
        asm volatile("" ::: "memory");
    }
    #undef STAGE_CB

    // merge across the 4 aq-lanes holding the same f-row, then global merge
    #pragma unroll
    for (int j = 0; j < J; ++j) {
        unsigned u = __float_as_uint(bestd[j]);
        u = (u & 0x80000000u) ? ~u : (u | 0x80000000u);
        unsigned long long p = ((unsigned long long)u << 32) | (unsigned)bestk[j];
        unsigned long long o = shfl_xor_u64(p, 16);
        if (o < p) p = o;
        o = shfl_xor_u64(p, 32);
        if (o < p) p = o;
        if (aq == 0)
            atomicMin(&packed[r0 + w * 16 * J + j * 16 + arow], p);
    }
}

// ---------------------------------------------------------------------------
// Fused update: f_hat eliminated via f_hat == f - f_rest (v13).
__global__ void update_pool_kernel(const float* __restrict__ f,
                                   const float* __restrict__ emb,
                                   const unsigned long long* __restrict__ packed,
                                   float* __restrict__ f_rest,
                                   float* __restrict__ out,
                                   float* __restrict__ slots,
                                   u16* __restrict__ rest_bf, int pn) {
    int b = blockIdx.x;
    int c = threadIdx.x;
    __shared__ int sk[NN];
    __shared__ float red[4];
    if (threadIdx.x < pn)
        sk[threadIdx.x] = (int)(unsigned)(packed[b * pn + threadIdx.x] & 0xffffffffull);
    __syncthreads();

    float fr[NN];
    float acc_sq = 0.f;
    #pragma unroll
    for (int n = 0; n < NN; ++n) {
        double pos = (n + 0.5) * ((double)pn / 16.0) - 0.5;
        if (pos < 0.0) pos = 0.0;
        int i0 = (int)floor(pos);
        if (i0 > pn - 1) i0 = pn - 1;
        int i1 = i0 + 1;
        if (i1 > pn - 1) i1 = pn - 1;
        double frac = pos - (double)i0;
        float w1 = (float)frac;
        float w0 = (float)(1.0 - frac);
        float h = w0 * emb[(size_t)sk[i0] * CC + c] + w1 * emb[(size_t)sk[i1] * CC + c];
        size_t off = ((size_t)b * NN + n) * CC + c;
        float fre = f_rest[off] - h;
        fr[n] = fre;
        acc_sq += fre * fre;
        if (pn < NN) {
            f_rest[off] = fre;
        } else {
            out[off] = f[off] - fre;   // f_hat = f - f_rest
        }
    }

    int wv = threadIdx.x >> 6, ln = threadIdx.x & 63;
    #pragma unroll
    for (int m = 32; m >= 1; m >>= 1) acc_sq += __shfl_xor(acc_sq, m, 64);
    if (ln == 0) red[wv] = acc_sq;

    int pn2 = pn + 1;
    if (pn < NN) {
        for (int p = 0; p < pn2; ++p) {
            int s = (p * NN) / pn2;
            int e = ((p + 1) * NN + pn2 - 1) / pn2;
            float v = 0.f;
            for (int n = s; n < e; ++n) v += fr[n];
            v *= 1.0f / (float)(e - s);
            rest_bf[((size_t)(b * pn2 + p)) * CC + c] = f2bf(v);
        }
    }
    __syncthreads();
    if (threadIdx.x == 0)
        atomicAdd(&slots[b & 255], (red[0] + red[1]) + (red[2] + red[3]));
}

// ---------------------------------------------------------------------------
__global__ void final_kernel(const float* __restrict__ slots, float* __restrict__ out_scalars) {
    float v = slots[threadIdx.x];
    #pragma unroll
    for (int m = 32; m >= 1; m >>= 1) v += __shfl_xor(v, m, 64);
    __shared__ float red[4];
    int wv = threadIdx.x >> 6, ln = threadIdx.x & 63;
    if (ln == 0) red[wv] = v;
    __syncthreads();
    if (threadIdx.x == 0) {
        float S = (red[0] + red[1]) + (red[2] + red[3]);
        float qlat = S / (float)BNC / (float)NN;
        out_scalars[0] = 0.25f * qlat;   // commit
        out_scalars[1] = qlat;           // qlat
    }
}

// ---------------------------------------------------------------------------
extern "C" void kernel_launch(void* const* d_in, const int* in_sizes, int n_in,
                              void* d_out, int out_size, void* d_ws, size_t ws_size,
                              hipStream_t stream) {
    (void)in_sizes; (void)n_in; (void)out_size; (void)ws_size;
    const float* f   = (const float*)d_in[0];   // [B, N, C]
    const float* emb = (const float*)d_in[1];   // [K, C]
    float* out = (float*)d_out;                 // f_hat [B*N*C] + 2 scalars

    float* ws      = (float*)d_ws;
    float* f_rest  = ws;                                   // BNC floats
    float* r2_pad  = f_rest + BNC;                         // 8192 (unused, layout keep)
    float* e_sq    = r2_pad + BB * NN;                     // K (0.5*|e|^2)
    float* slots   = e_sq + KK;                            // 256
    unsigned long long* packed_all = (unsigned long long*)(slots + 256);  // 512*136
    u16* rest_bf = (u16*)(packed_all + (size_t)BB * 136);  // 8192*256 bf16
    u16* emb_bf  = rest_bf + (size_t)BB * NN * CC;         // K*C bf16 (negated)

    hipMemcpyAsync(f_rest, f, (size_t)BNC * sizeof(float), hipMemcpyDeviceToDevice, stream);
    hipMemsetAsync(slots, 0, 256 * sizeof(float), stream);
    hipMemsetAsync(packed_all, 0xFF, (size_t)BB * 136 * sizeof(unsigned long long), stream);
    esq_cvt_kernel<<<KK * CC / 4 / 256, 256, 0, stream>>>(emb, e_sq, emb_bf);
    init_pool_kernel<<<BB, 256, 0, stream>>>(f, rest_bf);

    // pn < 8: J=2 (256-row blocks, grid-x = 2*pn), v14 splits.
    // pn >= 8: J=4 (512-row blocks, grid-x = pn), splits -> ~256-480 blocks.
    static const int splits_tab2[8] = {0, 128, 128, 128, 64, 64, 64, 64};
    static const int splits_tab4[17] =
        {0,0,0,0,0,0,0,0, 32,32,32,32,32,32,32,32, 16};

    for (int pn = 1; pn <= NN; ++pn) {
        unsigned long long* packed = packed_all + (size_t)BB * (pn * (pn - 1) / 2);
        if (pn < 8) {
            int splits = splits_tab2[pn];
            int cpb = KK / splits;
            dim3 grid(BB * pn / 256, splits);
            dist_mfma_kernel<2><<<grid, 512, 0, stream>>>(rest_bf, emb_bf, e_sq,
                                                          packed, cpb);
        } else {
            int splits = splits_tab4[pn];
            int cpb = KK / splits;
            dim3 grid(BB * pn / 512, splits);
            dist_mfma_kernel<4><<<grid, 512, 0, stream>>>(rest_bf, emb_bf, e_sq,
                                                          packed, cpb);
        }
        update_pool_kernel<<<BB, 256, 0, stream>>>(f, emb, packed, f_rest, out,
                                                   slots, rest_bf, pn);
    }
    final_kernel<<<1, 256, 0, stream>>>(slots, out + BNC);
}

// Round 16
// 662.743 us; speedup vs baseline: 1.1122x; 1.1122x over previous
//
#include <hip/hip_runtime.h>
#include <math.h>

#define BB 512
#define NN 16
#define CC 256
#define KK 8192
#define BNC (BB*NN*CC)

typedef unsigned short u16;
typedef __attribute__((ext_vector_type(8))) short bf16x8;
typedef __attribute__((ext_vector_type(4))) float f32x4;

__device__ __forceinline__ u16 f2bf(float x) {
    unsigned u = __float_as_uint(x);
    unsigned r = (u + 0x7fffu + ((u >> 16) & 1u)) >> 16;
    return (u16)r;
}

__device__ __forceinline__ void gl2lds16(const void* g, void* l) {
    __builtin_amdgcn_global_load_lds(
        (const __attribute__((address_space(1))) void*)g,
        (__attribute__((address_space(3))) void*)l,
        16, 0, 0);
}

__device__ __forceinline__ void gl2lds4(const void* g, void* l) {
    __builtin_amdgcn_global_load_lds(
        (const __attribute__((address_space(1))) void*)g,
        (__attribute__((address_space(3))) void*)l,
        4, 0, 0);
}

// ---------------------------------------------------------------------------
// merged: stores negated-bf16 emb AND 0.5*|e|^2 from one pass over emb.
__global__ void esq_cvt_kernel(const float* __restrict__ emb,
                               float* __restrict__ e_sq,
                               u16* __restrict__ out) {
    int gid = blockIdx.x * blockDim.x + threadIdx.x;
    int lane = gid & 63;
    float4 v = ((const float4*)emb)[gid];
    ushort4 o;
    o.x = f2bf(-v.x); o.y = f2bf(-v.y); o.z = f2bf(-v.z); o.w = f2bf(-v.w);
    ((ushort4*)out)[gid] = o;
    float s = v.x*v.x + v.y*v.y + v.z*v.z + v.w*v.w;
    #pragma unroll
    for (int m = 32; m >= 1; m >>= 1) s += __shfl_xor(s, m, 64);
    if (lane == 0) e_sq[gid >> 6] = 0.5f * s;
}

// initial pool for pn=1
__global__ void init_pool_kernel(const float* __restrict__ f,
                                 u16* __restrict__ rest_bf) {
    int b = blockIdx.x;
    int c = threadIdx.x;
    const float* base = f + (size_t)b * NN * CC + c;
    float acc = 0.f;
    #pragma unroll
    for (int n = 0; n < NN; ++n) acc += base[(size_t)n * CC];
    rest_bf[(size_t)b * CC + c] = f2bf(acc * (1.0f / 16.0f));
}

// ---------------------------------------------------------------------------
__device__ __forceinline__ unsigned long long shfl_xor_u64(unsigned long long v, int m) {
    unsigned lo = (unsigned)v, hi = (unsigned)(v >> 32);
    lo = __shfl_xor(lo, m, 64);
    hi = __shfl_xor(hi, m, 64);
    return ((unsigned long long)hi << 32) | lo;
}

// MFMA distance+argmin, v17 (= v14, the best measured configuration):
//  Frontier mapped over v5-v16: read-economy (J) vs waves/SIMD is a hard
//  register trade (bf residency = 32J VGPR): J=2 fits the 128-reg class
//  (4 waves/SIMD, LDS-read-bound ~50%), J=4 needs the 256-reg class
//  (2 waves/SIMD, latency-bound). Both corners measure 43-47us @pn=16
//  across six sync structures; v14 (J=2, 512-thread, 8 waves, 66KB LDS,
//  cb-drain schedule) gave the best total (662.7us). Locked in.
__global__ __launch_bounds__(512, 2) void dist_mfma_kernel(
        const u16* __restrict__ A, const u16* __restrict__ Bm,
        const float* __restrict__ e_sq,
        unsigned long long* __restrict__ packed, int cpb) {
    __shared__ __align__(16) u16 sC[32768];   // 64KB: 2 cb-buffers x 32KB
    __shared__ __align__(16) float sE[512];   // whole esq strip for this block
    const int tid = threadIdx.x;
    const int w = tid >> 6, l = tid & 63;     // 8 waves
    const int r0 = blockIdx.x * 256;
    const int c0 = blockIdx.y * cpb;
    const int ncb2 = cpb >> 6;   // 64-code cb-groups
    const int arow = l & 15;
    const int aq   = l >> 4;

    // ---- resident row fragments: wave owns rows r0+w*32 .. +31 ----
    bf16x8 bf[2][8];
    {
        const u16* fb = A + (((size_t)(r0 + w * 32 + arow)) << 8) + aq * 8;
        #pragma unroll
        for (int j = 0; j < 2; ++j)
            #pragma unroll
            for (int kc = 0; kc < 8; ++kc)
                bf[j][kc] = *(const bf16x8*)(fb + (j << 12) + (kc << 5));
    }

    // ---- esq strip staged whole in prologue (cpb <= 512) ----
    for (int n = tid; n < cpb; n += 512)
        gl2lds4(e_sq + c0 + n, (char*)sE + (size_t)(n - l) * 4);

    // ---- code staging: wave w stages chunk w (k-dims [w*32, w*32+32)).
    // issue i covers codes i*16 + (l>>2); stored granule (l&3) receives
    // actual granule g = (l&3)^((l>>3)&3) (pre-swizzled source).
    const int g = (l & 3) ^ ((l >> 3) & 3);
    const u16* Pb = Bm + (((size_t)(c0 + (l >> 2))) << 8) + g * 8;

    #define STAGE_CB(cb_) { \
        const u16* s0_ = Pb + ((size_t)(cb_) << 14) + (w << 5); \
        char* d0_ = (char*)sC + (((cb_) & 1) << 15) + (w << 12); \
        _Pragma("unroll") \
        for (int i_ = 0; i_ < 4; ++i_) \
            gl2lds16(s0_ + (i_ << 12), d0_ + (i_ << 10)); }

    STAGE_CB(0)

    const int gx = aq ^ ((arow >> 1) & 3);   // read-side granule swizzle
    float bestd[2];
    int   bestk[2];
    #pragma unroll
    for (int j = 0; j < 2; ++j) { bestd[j] = 1e30f; bestk[j] = 0; }

    asm volatile("s_waitcnt vmcnt(0)" ::: "memory");
    __builtin_amdgcn_s_barrier();
    asm volatile("" ::: "memory");

    for (int cb = 0; cb < ncb2; ++cb) {
        // burst-issue next cb's stages (max flight time before the drain)
        if (cb + 1 < ncb2) STAGE_CB(cb + 1)

        f32x4 acc[4][2];
        #pragma unroll
        for (int i = 0; i < 4; ++i) {
            f32x4 ev = *(const f32x4*)(sE + cb * 64 + i * 16 + (aq << 2));
            #pragma unroll
            for (int j = 0; j < 2; ++j) acc[i][j] = ev;
        }

        const u16* bufp = sC + ((cb & 1) << 14);   // u16 units: 32KB buffer
        #pragma unroll
        for (int c = 0; c < 8; ++c) {
            bf16x8 cf[4];
            const u16* cbp = bufp + (c << 11);
            #pragma unroll
            for (int i = 0; i < 4; ++i)
                cf[i] = *(const bf16x8*)(cbp + ((i * 16 + arow) << 5) + (gx << 3));
            #pragma unroll
            for (int i = 0; i < 4; ++i)
                #pragma unroll
                for (int j = 0; j < 2; ++j)
                    acc[i][j] = __builtin_amdgcn_mfma_f32_16x16x32_bf16(
                                    cf[i], bf[j][c], acc[i][j], 0, 0, 0);
        }

        // fold (register-only; overlaps tail of in-flight stages)
        #pragma unroll
        for (int i = 0; i < 4; ++i)
            #pragma unroll
            for (int r = 0; r < 4; ++r) {
                const int k = c0 + cb * 64 + i * 16 + (aq << 2) + r;
                #pragma unroll
                for (int j = 0; j < 2; ++j) {
                    const float d = acc[i][j][r];
                    if (d < bestd[j]) { bestd[j] = d; bestk[j] = k; }
                }
            }

        // own stages for cb+1 complete; reads of this buffer retired
        asm volatile("s_waitcnt vmcnt(0) lgkmcnt(0)" ::: "memory");
        __builtin_amdgcn_s_barrier();
        asm volatile("" ::: "memory");
    }
    #undef STAGE_CB

    // merge across the 4 aq-lanes holding the same f-row, then global merge
    #pragma unroll
    for (int j = 0; j < 2; ++j) {
        unsigned u = __float_as_uint(bestd[j]);
        u = (u & 0x80000000u) ? ~u : (u | 0x80000000u);
        unsigned long long p = ((unsigned long long)u << 32) | (unsigned)bestk[j];
        unsigned long long o = shfl_xor_u64(p, 16);
        if (o < p) p = o;
        o = shfl_xor_u64(p, 32);
        if (o < p) p = o;
        if (aq == 0)
            atomicMin(&packed[r0 + w * 32 + j * 16 + arow], p);
    }
}

// ---------------------------------------------------------------------------
// Fused update: f_hat eliminated via f_hat == f - f_rest (v13).
__global__ void update_pool_kernel(const float* __restrict__ f,
                                   const float* __restrict__ emb,
                                   const unsigned long long* __restrict__ packed,
                                   float* __restrict__ f_rest,
                                   float* __restrict__ out,
                                   float* __restrict__ slots,
                                   u16* __restrict__ rest_bf, int pn) {
    int b = blockIdx.x;
    int c = threadIdx.x;
    __shared__ int sk[NN];
    __shared__ float red[4];
    if (threadIdx.x < pn)
        sk[threadIdx.x] = (int)(unsigned)(packed[b * pn + threadIdx.x] & 0xffffffffull);
    __syncthreads();

    float fr[NN];
    float acc_sq = 0.f;
    #pragma unroll
    for (int n = 0; n < NN; ++n) {
        double pos = (n + 0.5) * ((double)pn / 16.0) - 0.5;
        if (pos < 0.0) pos = 0.0;
        int i0 = (int)floor(pos);
        if (i0 > pn - 1) i0 = pn - 1;
        int i1 = i0 + 1;
        if (i1 > pn - 1) i1 = pn - 1;
        double frac = pos - (double)i0;
        float w1 = (float)frac;
        float w0 = (float)(1.0 - frac);
        float h = w0 * emb[(size_t)sk[i0] * CC + c] + w1 * emb[(size_t)sk[i1] * CC + c];
        size_t off = ((size_t)b * NN + n) * CC + c;
        float fre = f_rest[off] - h;
        fr[n] = fre;
        acc_sq += fre * fre;
        if (pn < NN) {
            f_rest[off] = fre;
        } else {
            out[off] = f[off] - fre;   // f_hat = f - f_rest
        }
    }

    int wv = threadIdx.x >> 6, ln = threadIdx.x & 63;
    #pragma unroll
    for (int m = 32; m >= 1; m >>= 1) acc_sq += __shfl_xor(acc_sq, m, 64);
    if (ln == 0) red[wv] = acc_sq;

    int pn2 = pn + 1;
    if (pn < NN) {
        for (int p = 0; p < pn2; ++p) {
            int s = (p * NN) / pn2;
            int e = ((p + 1) * NN + pn2 - 1) / pn2;
            float v = 0.f;
            for (int n = s; n < e; ++n) v += fr[n];
            v *= 1.0f / (float)(e - s);
            rest_bf[((size_t)(b * pn2 + p)) * CC + c] = f2bf(v);
        }
    }
    __syncthreads();
    if (threadIdx.x == 0)
        atomicAdd(&slots[b & 255], (red[0] + red[1]) + (red[2] + red[3]));
}

// ---------------------------------------------------------------------------
__global__ void final_kernel(const float* __restrict__ slots, float* __restrict__ out_scalars) {
    float v = slots[threadIdx.x];
    #pragma unroll
    for (int m = 32; m >= 1; m >>= 1) v += __shfl_xor(v, m, 64);
    __shared__ float red[4];
    int wv = threadIdx.x >> 6, ln = threadIdx.x & 63;
    if (ln == 0) red[wv] = v;
    __syncthreads();
    if (threadIdx.x == 0) {
        float S = (red[0] + red[1]) + (red[2] + red[3]);
        float qlat = S / (float)BNC / (float)NN;
        out_scalars[0] = 0.25f * qlat;   // commit
        out_scalars[1] = qlat;           // qlat
    }
}

// ---------------------------------------------------------------------------
extern "C" void kernel_launch(void* const* d_in, const int* in_sizes, int n_in,
                              void* d_out, int out_size, void* d_ws, size_t ws_size,
                              hipStream_t stream) {
    (void)in_sizes; (void)n_in; (void)out_size; (void)ws_size;
    const float* f   = (const float*)d_in[0];   // [B, N, C]
    const float* emb = (const float*)d_in[1];   // [K, C]
    float* out = (float*)d_out;                 // f_hat [B*N*C] + 2 scalars

    float* ws      = (float*)d_ws;
    float* f_rest  = ws;                                   // BNC floats
    float* r2_pad  = f_rest + BNC;                         // 8192 (unused, layout keep)
    float* e_sq    = r2_pad + BB * NN;                     // K (0.5*|e|^2)
    float* slots   = e_sq + KK;                            // 256
    unsigned long long* packed_all = (unsigned long long*)(slots + 256);  // 512*136
    u16* rest_bf = (u16*)(packed_all + (size_t)BB * 136);  // 8192*256 bf16
    u16* emb_bf  = rest_bf + (size_t)BB * NN * CC;         // K*C bf16 (negated)

    hipMemcpyAsync(f_rest, f, (size_t)BNC * sizeof(float), hipMemcpyDeviceToDevice, stream);
    hipMemsetAsync(slots, 0, 256 * sizeof(float), stream);
    hipMemsetAsync(packed_all, 0xFF, (size_t)BB * 136 * sizeof(unsigned long long), stream);
    esq_cvt_kernel<<<KK * CC / 4 / 256, 256, 0, stream>>>(emb, e_sq, emb_bf);
    init_pool_kernel<<<BB, 256, 0, stream>>>(f, rest_bf);

    // splits: target >= 512 blocks where cpb >= 64 allows; cpb = 8192/splits
    static const int splits_tab[17] =
        {0,128,128,128,64,64,64,64,32,32,32,32,32,32,32,32,16};

    for (int pn = 1; pn <= NN; ++pn) {
        unsigned long long* packed = packed_all + (size_t)BB * (pn * (pn - 1) / 2);
        int splits = splits_tab[pn];
        int cpb = KK / splits;
        dim3 grid(BB * pn / 256, splits);
        dist_mfma_kernel<<<grid, 512, 0, stream>>>(rest_bf, emb_bf, e_sq, packed, cpb);
        update_pool_kernel<<<BB, 256, 0, stream>>>(f, emb, packed, f_rest, out,
                                                   slots, rest_bf, pn);
    }
    final_kernel<<<1, 256, 0, stream>>>(slots, out + BNC);
}